// Round 1
// baseline (642.561 us; speedup 1.0000x reference)
//
#include <hip/hip_runtime.h>

typedef unsigned int uint;
typedef unsigned short ushort;
typedef __attribute__((ext_vector_type(8))) short short8;
typedef __attribute__((ext_vector_type(4))) float f32x4;

#define Bb 4
#define Cc 256
#define Nn 4096

// ws byte offsets (total ~10.8 MB)
#define WALL_OFF 0x0       // 320*256 f32 = 327680 B
#define BALL_OFF 0x50000   // 320 f32
#define QBF_OFF  0x50800   // [b][n][32] bf16 = 1 MB
#define KBF_OFF  0x150800  // [b][n][32] bf16 = 1 MB
#define VBF_OFF  0x250800  // frag-major: [b][kt64][fid32][lane64][8] bf16 = 8 MB

__device__ __forceinline__ ushort f2bf(float f) {
  uint u = __float_as_uint(f);
  return (ushort)((u + 0x7FFFu + ((u >> 16) & 1u)) >> 16);
}

// ---------------- K0: pack weights ----------------
__global__ __launch_bounds__(256) void k0_pack(
    const float* __restrict__ Wq, const float* __restrict__ bq,
    const float* __restrict__ Wk, const float* __restrict__ bk,
    const float* __restrict__ Wv, const float* __restrict__ bv,
    float* __restrict__ wall, float* __restrict__ ball) {
  int idx = blockIdx.x * 256 + threadIdx.x;
  if (idx < 320 * 256) {
    int O = idx >> 8, c = idx & 255;
    float v;
    if (O < 32) v = Wq[O * 256 + c];
    else if (O < 64) v = Wk[(O - 32) * 256 + c];
    else v = Wv[(O - 64) * 256 + c];
    wall[idx] = v;
  } else {
    int i = idx - 320 * 256;
    if (i < 320)
      ball[i] = (i < 32) ? bq[i] : (i < 64) ? bk[i - 32] : bv[i - 64];
  }
}

// ---------------- K1: q,k,v projections ----------------
// block: (b, n-tile of 64). 4 waves; wave og owns outputs [og*80, og*80+80).
__global__ __launch_bounds__(256) void k1_qkv(
    const float* __restrict__ x, const float* __restrict__ wall,
    const float* __restrict__ ball, ushort* __restrict__ qbf,
    ushort* __restrict__ kbf, ushort* __restrict__ vbf) {
  int bx = blockIdx.x;
  int b = bx >> 6, nt = bx & 63;
  int t = threadIdx.x;
  int lane = t & 63;
  int og = __builtin_amdgcn_readfirstlane(t >> 6);
  int n = nt * 64 + lane;
  const float* xp = x + (size_t)b * Cc * Nn + n;
  const float* wp = wall + og * 80 * 256;
  const float* bp = ball + og * 80;
  float acc[80];
#pragma unroll
  for (int j = 0; j < 80; ++j) acc[j] = bp[j];
  for (int c = 0; c < 256; ++c) {
    float xv = xp[(size_t)c * Nn];
#pragma unroll
    for (int j = 0; j < 80; ++j)
      acc[j] = fmaf(wp[j * 256 + c], xv, acc[j]);
  }
  // v frag-major coords from n
  int kt = n >> 6, kl = n & 63;
  int kk = kl >> 5, klo = kl & 31;
  int g = (klo >> 2) & 3;
  int i2 = (klo & 3) + 4 * (klo >> 4);
  size_t npart = (((size_t)b * 64 + kt) * 32 + kk) * 512 + (16 * g) * 8 + i2;
  if (og == 0) {
    size_t qk = ((size_t)(b * Nn + n)) * 32;
#pragma unroll
    for (int j = 0; j < 32; ++j) qbf[qk + j] = f2bf(acc[j]);
#pragma unroll
    for (int j = 32; j < 64; ++j) kbf[qk + (j - 32)] = f2bf(acc[j]);
#pragma unroll
    for (int j = 64; j < 80; ++j) {
      int c = j - 64;
      int fi = c >> 4, lr = c & 15;
      vbf[npart + (size_t)(fi * 2) * 512 + lr * 8] = f2bf(acc[j]);
    }
  } else {
#pragma unroll
    for (int j = 0; j < 80; ++j) {
      int c = og * 80 - 64 + j;
      int fi = c >> 4, lr = c & 15;
      vbf[npart + (size_t)(fi * 2) * 512 + lr * 8] = f2bf(acc[j]);
    }
  }
}

// ---------------- K2: scores (MFMA) + softmax + attn write ----------------
// block: (b, 16-row n-tile), 256 thr / 4 waves; wave w does m-frags w+4i.
__global__ __launch_bounds__(256) void k2_scores(
    const ushort* __restrict__ qbf, const ushort* __restrict__ kbf,
    float* __restrict__ attn) {
  int bx = blockIdx.x;
  int b = bx >> 8, ntile = bx & 255;
  int t = threadIdx.x, lane = t & 63, w = t >> 6;
  int lr = lane & 15, g = lane >> 4;
  int n0 = ntile * 16;
  const ushort* kp = kbf + ((size_t)(b * Nn + n0 + lr)) * 32 + 4 * g;
  short8 afr;
  ((uint2*)&afr)[0] = *(const uint2*)kp;
  ((uint2*)&afr)[1] = *(const uint2*)(kp + 16);
  const f32x4 z = {0.f, 0.f, 0.f, 0.f};
  float psum[4] = {0.f, 0.f, 0.f, 0.f};
  const ushort* qbase = qbf + (size_t)b * Nn * 32 + (size_t)lr * 32 + 4 * g;
  for (int i = 0; i < 64; ++i) {
    int mf = w + 4 * i;
    const ushort* qp = qbase + (size_t)mf * 512;
    short8 bfr;
    ((uint2*)&bfr)[0] = *(const uint2*)qp;
    ((uint2*)&bfr)[1] = *(const uint2*)(qp + 16);
    f32x4 sc = __builtin_amdgcn_mfma_f32_16x16x32_bf16(afr, bfr, z, 0, 0, 0);
#pragma unroll
    for (int r = 0; r < 4; ++r) psum[r] += __expf(sc[r]);
  }
#pragma unroll
  for (int m = 1; m <= 8; m <<= 1) {
#pragma unroll
    for (int r = 0; r < 4; ++r) psum[r] += __shfl_xor(psum[r], m, 64);
  }
  __shared__ float sums[4][16];
  __shared__ float inv[16];
  if (lr == 0) {
#pragma unroll
    for (int r = 0; r < 4; ++r) sums[w][4 * g + r] = psum[r];
  }
  __syncthreads();
  if (t < 16) inv[t] = 1.0f / (sums[0][t] + sums[1][t] + sums[2][t] + sums[3][t]);
  __syncthreads();
  float vinv[4];
#pragma unroll
  for (int r = 0; r < 4; ++r) vinv[r] = inv[4 * g + r];
  float* ap = attn + ((size_t)(b * Nn + n0)) * Nn;
  for (int i = 0; i < 64; ++i) {
    int mf = w + 4 * i;
    const ushort* qp = qbase + (size_t)mf * 512;
    short8 bfr;
    ((uint2*)&bfr)[0] = *(const uint2*)qp;
    ((uint2*)&bfr)[1] = *(const uint2*)(qp + 16);
    f32x4 sc = __builtin_amdgcn_mfma_f32_16x16x32_bf16(afr, bfr, z, 0, 0, 0);
#pragma unroll
    for (int r = 0; r < 4; ++r)
      ap[(size_t)(4 * g + r) * Nn + mf * 16 + lr] = __expf(sc[r]) * vinv[r];
  }
}

// ---------------- K3: out = gamma * (V @ attn) + x  (MFMA GEMM) ----------------
// tile 256(c) x 64(m), BK=64, 512 thr / 8 waves (4 row x 2 col).
__global__ __launch_bounds__(512) void k3_pv(
    const float* __restrict__ attn, const ushort* __restrict__ vbf,
    const float* __restrict__ x, const float* __restrict__ gamma,
    float* __restrict__ out) {
  __shared__ __align__(16) ushort Alds[16384];  // 32 frags x 64 lanes x 8 bf16
  __shared__ __align__(16) ushort Blds[4096];   // 8 frags x 64 lanes x 8 bf16
  int bx = blockIdx.x;
  int b = bx >> 6, mt = bx & 63;
  int t = threadIdx.x, lane = t & 63, wid = t >> 6;
  int wr = wid >> 1, wc = wid & 1;
  f32x4 z = {0.f, 0.f, 0.f, 0.f};
  f32x4 acc[4][2];
#pragma unroll
  for (int fi = 0; fi < 4; ++fi)
#pragma unroll
    for (int fj = 0; fj < 2; ++fj) acc[fi][fj] = z;
  const ushort* vsrc = vbf + (size_t)b * 64 * 16384;
  int ml = t & 63, kg = t >> 6;  // B-staging coords
  int fjg_w = ml >> 4, bkk = kg >> 2, h = (kg >> 1) & 1;
  const float* bsrc = attn + ((size_t)b * Nn + kg * 8) * Nn + mt * 64 + ml;
  for (int kt = 0; kt < 64; ++kt) {
    __syncthreads();
    {  // stage A: linear copy of frag-major tile (coalesced, conflict-free)
      const short8* s = (const short8*)(vsrc + (size_t)kt * 16384);
      short8* d = (short8*)Alds;
#pragma unroll
      for (int i = 0; i < 4; ++i) d[t + i * 512] = s[t + i * 512];
    }
    {  // stage B: attn fp32 -> bf16 transpose into frag-major
      const float* bp = bsrc + (size_t)kt * 64 * Nn;
#pragma unroll
      for (int u = 0; u < 2; ++u) {
        float s0 = bp[(size_t)(u * 4 + 0) * Nn];
        float s1 = bp[(size_t)(u * 4 + 1) * Nn];
        float s2 = bp[(size_t)(u * 4 + 2) * Nn];
        float s3 = bp[(size_t)(u * 4 + 3) * Nn];
        uint2 pk;
        pk.x = (uint)f2bf(s0) | ((uint)f2bf(s1) << 16);
        pk.y = (uint)f2bf(s2) | ((uint)f2bf(s3) << 16);
        int g_s = (kg & 1) * 2 + u;
        int off = ((fjg_w * 2 + bkk) * 64 + (ml & 15) + 16 * g_s) * 16 + h * 8;
        *(uint2*)((char*)Blds + off) = pk;
      }
    }
    __syncthreads();
#pragma unroll
    for (int kk = 0; kk < 2; ++kk) {
      short8 af[4], bf[2];
#pragma unroll
      for (int fi = 0; fi < 4; ++fi)
        af[fi] = ((const short8*)Alds)[((wr * 4 + fi) * 2 + kk) * 64 + lane];
#pragma unroll
      for (int fj = 0; fj < 2; ++fj)
        bf[fj] = ((const short8*)Blds)[((wc * 2 + fj) * 2 + kk) * 64 + lane];
#pragma unroll
      for (int fi = 0; fi < 4; ++fi)
#pragma unroll
        for (int fj = 0; fj < 2; ++fj)
          acc[fi][fj] = __builtin_amdgcn_mfma_f32_16x16x32_bf16(af[fi], bf[fj], acc[fi][fj], 0, 0, 0);
    }
  }
  float gm = gamma[0];
  int g = lane >> 4, lr = lane & 15;
#pragma unroll
  for (int fi = 0; fi < 4; ++fi) {
#pragma unroll
    for (int fj = 0; fj < 2; ++fj) {
#pragma unroll
      for (int r = 0; r < 4; ++r) {
        int c = (wr * 4 + fi) * 16 + 4 * g + r;
        int m = mt * 64 + (wc * 2 + fj) * 16 + lr;
        size_t idx = ((size_t)b * Cc + c) * Nn + m;
        out[idx] = gm * acc[fi][fj][r] + x[idx];
      }
    }
  }
}

extern "C" void kernel_launch(void* const* d_in, const int* in_sizes, int n_in,
                              void* d_out, int out_size, void* d_ws, size_t ws_size,
                              hipStream_t stream) {
  const float* x = (const float*)d_in[0];
  const float* Wq = (const float*)d_in[1];
  const float* bq = (const float*)d_in[2];
  const float* Wk = (const float*)d_in[3];
  const float* bk = (const float*)d_in[4];
  const float* Wv = (const float*)d_in[5];
  const float* bv = (const float*)d_in[6];
  const float* gamma = (const float*)d_in[7];
  float* out = (float*)d_out;
  float* attn = out + (size_t)Bb * Cc * Nn;
  char* ws = (char*)d_ws;
  float* wall = (float*)(ws + WALL_OFF);
  float* ball = (float*)(ws + BALL_OFF);
  ushort* qbf = (ushort*)(ws + QBF_OFF);
  ushort* kbf = (ushort*)(ws + KBF_OFF);
  ushort* vbf = (ushort*)(ws + VBF_OFF);
  hipLaunchKernelGGL(k0_pack, dim3(322), dim3(256), 0, stream,
                     Wq, bq, Wk, bk, Wv, bv, wall, ball);
  hipLaunchKernelGGL(k1_qkv, dim3(256), dim3(256), 0, stream,
                     x, wall, ball, qbf, kbf, vbf);
  hipLaunchKernelGGL(k2_scores, dim3(Bb * 256), dim3(256), 0, stream,
                     qbf, kbf, attn);
  hipLaunchKernelGGL(k3_pv, dim3(256), dim3(512), 0, stream,
                     attn, vbf, x, gamma, out);
}